// Round 1
// 157.119 us; speedup vs baseline: 1.0153x; 1.0153x over previous
//
#include <hip/hip_runtime.h>

typedef float f32x4 __attribute__((ext_vector_type(4)));
typedef short short8 __attribute__((ext_vector_type(8)));
typedef _Float16 half8 __attribute__((ext_vector_type(8)));

#define SEQ_LEN 32
#define EMBED_DIM 64
#define FC_DIM 100
#define BATCH 512
#define AS 136      // f16 row stride for A_s/B_s: 272B = odd*16B -> 2-way bank alias (free)
#define ES 72       // f16 row stride for emb_s: 144B -> 2-way bank alias (free)

// 16B MFMA operand fragment. f16 frag for mfma_f32_16x16x32_f16 is 8 halves (4 VGPRs).
union Frag {
  half8 h8;
  _Float16 h[8];
  short8 s;
  unsigned int u[4];
};

// All global tensors are fp32 (JAX defaults). Internal precision is fp16
// (10-bit mantissa, strictly better than the previous bf16 path); all MFMA
// accumulation is fp32.
//
// One block per batch element. 256 threads = 4 waves, 2 blocks/CU.
// A: gather embedding rows, fp32 -> fp16 -> LDS.
// B: first FC via MFMA (M=32, N=208, K=64): A_s[c][f]=embs.Wa^T,
//    B_s[a][f]=embs.Wb^T + b1, packed fp16 in LDS (cols 100..127 zero pad).
// D: pair loop: per group (16 c-rows, 8 a's): h1 = relu(A+B) via v_pk_add_f16 +
//    v_pk_max_f16 directly in A-fragment layout (no cvt, no repack), constant
//    1.0 inserted at k=100 so the MFMA itself adds bf2 (wfrag k=100 slot holds
//    bf2[g]); second relu + M-reduce in epilogue.
// E: LDS tree-reduce column sums -> x_s[100].
// F: out[b,t] = b2[iv] + W2[iv,:].concat(x_s, uemb), fp32, wave shuffle reduce.
__global__ __launch_bounds__(256, 2) void cosrec_fused(
    const int* __restrict__ seq_var, const int* __restrict__ user_var,
    const int* __restrict__ item_var, const float* __restrict__ item_emb,
    const float* __restrict__ user_emb, const float* __restrict__ W2,
    const float* __restrict__ b2, const float* __restrict__ W1,
    const float* __restrict__ b1, const float* __restrict__ Wf2,
    const float* __restrict__ bf2, float* __restrict__ out)
{
  __shared__ __align__(16) _Float16 A_s[SEQ_LEN * AS];
  __shared__ __align__(16) _Float16 B_s[SEQ_LEN * AS];
  __shared__ float red_s[16 * 112];
  __shared__ float x_s[112];
  __shared__ __align__(16) _Float16 emb_s[SEQ_LEN * ES];

  const int b = blockIdx.x;
  const int t = threadIdx.x;
  const int w = t >> 6;
  const int l = t & 63;
  const int l15 = l & 15;
  const int q = l >> 4;
  // fp16 1.0 in h-slot k=100 (ks=3, q=0, j=4 -> low half of dword u[2])
  const unsigned int biasbits = (q == 0) ? 0x00003C00u : 0u;

  // ---- Phase A first: gather embedding rows (critical path to barrier) ----
  {
    const int r = t >> 3;                 // 0..31
    const int c0 = (t & 7) * 8;           // 8 cols per thread
    const int item = seq_var[b * SEQ_LEN + r];
    const float4 v0 = *(const float4*)(item_emb + item * EMBED_DIM + c0);
    const float4 v1 = *(const float4*)(item_emb + item * EMBED_DIM + c0 + 4);
    Frag e;
    e.h[0] = (_Float16)v0.x; e.h[1] = (_Float16)v0.y;
    e.h[2] = (_Float16)v0.z; e.h[3] = (_Float16)v0.w;
    e.h[4] = (_Float16)v1.x; e.h[5] = (_Float16)v1.y;
    e.h[6] = (_Float16)v1.z; e.h[7] = (_Float16)v1.w;
    *(short8*)(emb_s + r * ES + c0) = e.s;   // 16B-aligned
  }
  // zero k-pad cols 100..127 of A_s/B_s (dword writes, 2 halves each)
  for (int i = t; i < SEQ_LEN * 14; i += 256) {
    const int r = i / 14, d = (i % 14) * 2;
    *(unsigned int*)(A_s + r * AS + FC_DIM + d) = 0u;
    *(unsigned int*)(B_s + r * AS + FC_DIM + d) = 0u;
  }

  // ---- Wf2 -> register B-fragments (consumed only in Phase D; these global
  // loads drain behind the barrier + Phase B). lane: Wf2[g=nt*16+l15][k=ks*32+q*8+j]
  Frag wfrag[7][4];
  #pragma unroll
  for (int nt = 0; nt < 7; ++nt) {
    const int gg = nt * 16 + l15;
    const bool gok = (gg < FC_DIM);
    #pragma unroll
    for (int ks = 0; ks < 3; ++ks) {
      Frag f;
      if (gok) {                           // k = ks*32+q*8 .. +7 <= 95 < 100
        const float4 u0 = *(const float4*)(Wf2 + gg * FC_DIM + ks * 32 + q * 8);
        const float4 u1 = *(const float4*)(Wf2 + gg * FC_DIM + ks * 32 + q * 8 + 4);
        f.h[0] = (_Float16)u0.x; f.h[1] = (_Float16)u0.y;
        f.h[2] = (_Float16)u0.z; f.h[3] = (_Float16)u0.w;
        f.h[4] = (_Float16)u1.x; f.h[5] = (_Float16)u1.y;
        f.h[6] = (_Float16)u1.z; f.h[7] = (_Float16)u1.w;
      } else {
        f.u[0] = 0u; f.u[1] = 0u; f.u[2] = 0u; f.u[3] = 0u;
      }
      wfrag[nt][ks] = f;
    }
    // ks==3: k = 96 + q*8 + j. q==0 holds f=96..99 data, bf2 at k=100, rest 0.
    Frag f3;
    f3.u[0] = 0u; f3.u[1] = 0u; f3.u[2] = 0u; f3.u[3] = 0u;
    if (gok && q == 0) {
      const float4 u0 = *(const float4*)(Wf2 + gg * FC_DIM + 96);
      f3.h[0] = (_Float16)u0.x; f3.h[1] = (_Float16)u0.y;
      f3.h[2] = (_Float16)u0.z; f3.h[3] = (_Float16)u0.w;
      f3.h[4] = (_Float16)bf2[gg];         // bias folded into MFMA
    }
    wfrag[nt][3] = f3;
  }
  __syncthreads();

  // ---- Phase B: first FC via MFMA. o<100 -> A_s col o; 100<=o<200 -> B_s col o-100
  for (int nt = w; nt < 13; nt += 4) {
    const int o = nt * 16 + l15;
    int wr = 0, wc = 0;
    bool valid = true;
    if (o < FC_DIM)            { wr = o;          wc = 0;  }   // Wa = W1[:, :64]
    else if (o < 2 * FC_DIM)   { wr = o - FC_DIM; wc = 64; }   // Wb = W1[:, 64:]
    else valid = false;
    Frag bfr[2];
    #pragma unroll
    for (int ks = 0; ks < 2; ++ks) {
      if (valid) {
        const float* p = W1 + wr * 128 + wc + ks * 32 + q * 8;  // 32B-aligned
        const float4 u0 = *(const float4*)p;
        const float4 u1 = *(const float4*)(p + 4);
        bfr[ks].h[0] = (_Float16)u0.x; bfr[ks].h[1] = (_Float16)u0.y;
        bfr[ks].h[2] = (_Float16)u0.z; bfr[ks].h[3] = (_Float16)u0.w;
        bfr[ks].h[4] = (_Float16)u1.x; bfr[ks].h[5] = (_Float16)u1.y;
        bfr[ks].h[6] = (_Float16)u1.z; bfr[ks].h[7] = (_Float16)u1.w;
      } else {
        bfr[ks].u[0] = 0u; bfr[ks].u[1] = 0u; bfr[ks].u[2] = 0u; bfr[ks].u[3] = 0u;
      }
    }
    const float b1v = (o >= FC_DIM && o < 2 * FC_DIM) ? b1[o - FC_DIM] : 0.f;
    #pragma unroll
    for (int mt = 0; mt < 2; ++mt) {
      Frag afr[2];
      #pragma unroll
      for (int ks = 0; ks < 2; ++ks)
        afr[ks].s = *(const short8*)(emb_s + (mt * 16 + l15) * ES + ks * 32 + q * 8);
      f32x4 acc = {0.f, 0.f, 0.f, 0.f};
      #pragma unroll
      for (int ks = 0; ks < 2; ++ks)
        acc = __builtin_amdgcn_mfma_f32_16x16x32_f16(afr[ks].h8, bfr[ks].h8, acc, 0, 0, 0);
      const int row = mt * 16 + q * 4;   // D: col = lane&15, row = quad*4 + reg
      if (o < FC_DIM) {
        #pragma unroll
        for (int r = 0; r < 4; ++r)
          A_s[(row + r) * AS + o] = (_Float16)acc[r];
      } else if (o < 2 * FC_DIM) {
        #pragma unroll
        for (int r = 0; r < 4; ++r)
          B_s[(row + r) * AS + (o - FC_DIM)] = (_Float16)(acc[r] + b1v);
      }
    }
  }
  __syncthreads();

  // ---- Phase D: pair loop. Group = (c-half: 16 rows, 8 consecutive a's) ----
  float colsum[7];
  #pragma unroll
  for (int nt = 0; nt < 7; ++nt) colsum[nt] = 0.f;
  const half8 hzero = {};

  for (int g = w; g < 8; g += 4) {       // 2 groups per wave
    const int c = (g & 1) * 16 + l15;    // this lane's c-row (MFMA m-index)
    const int a0 = (g >> 1) * 8;
    Frag areg[4];                         // lane's A row in fragment order
    #pragma unroll
    for (int ks = 0; ks < 4; ++ks)
      areg[ks].s = *(const short8*)(A_s + c * AS + ks * 32 + q * 8);
    for (int ai = 0; ai < 8; ++ai) {
      const _Float16* bp = B_s + (a0 + ai) * AS;   // broadcast reads
      Frag hf[4];
      #pragma unroll
      for (int ks = 0; ks < 4; ++ks) {
        Frag br;
        br.s = *(const short8*)(bp + ks * 32 + q * 8);
        const half8 sum = areg[ks].h8 + br.h8;      // v_pk_add_f16 x4
        hf[ks].h8 = __builtin_elementwise_max(sum, hzero);  // v_pk_max_f16 x4
      }
      hf[3].u[2] |= biasbits;                       // h=1.0 at k=100 (bias slot)
      #pragma unroll
      for (int nt = 0; nt < 7; ++nt) {
        f32x4 acc = {0.f, 0.f, 0.f, 0.f};
        #pragma unroll
        for (int ks = 0; ks < 4; ++ks)
          acc = __builtin_amdgcn_mfma_f32_16x16x32_f16(hf[ks].h8, wfrag[nt][ks].h8, acc, 0, 0, 0);
        #pragma unroll
        for (int r = 0; r < 4; ++r)
          colsum[nt] += fmaxf(acc[r], 0.f);   // second relu + M-reduce (bias in acc)
      }
    }
  }

  // ---- Phase E: reduce colsum across (wave, quad) via LDS ----
  #pragma unroll
  for (int nt = 0; nt < 7; ++nt)
    red_s[(w * 4 + q) * 112 + nt * 16 + l15] = colsum[nt];
  __syncthreads();
  if (t < 112) {
    float s = 0.f;
    #pragma unroll
    for (int r = 0; r < 16; ++r) s += red_s[r * 112 + t];
    x_s[t] = s;
  }
  __syncthreads();

  // ---- Phase F: out[b,w] = b2[iv] + W2[iv,:].concat(x_s, uemb), wave reduce ----
  if (w < 3) {
    const int iv = item_var[b * 3 + w];
    const int uu = user_var[b];
    float partial = 0.f;
    for (int idx = l; idx < FC_DIM + EMBED_DIM; idx += 64) {
      const float xv = (idx < FC_DIM)
                           ? x_s[idx]
                           : user_emb[uu * EMBED_DIM + (idx - FC_DIM)];
      partial += W2[iv * (FC_DIM + EMBED_DIM) + idx] * xv;
    }
    #pragma unroll
    for (int off = 32; off > 0; off >>= 1)
      partial += __shfl_down(partial, off, 64);
    if (l == 0) out[b * 3 + w] = partial + b2[iv];
  }
}

extern "C" void kernel_launch(void* const* d_in, const int* in_sizes, int n_in,
                              void* d_out, int out_size, void* d_ws, size_t ws_size,
                              hipStream_t stream) {
  const int* seq = (const int*)d_in[0];
  const int* usr = (const int*)d_in[1];
  const int* itm = (const int*)d_in[2];
  const float* item_emb = (const float*)d_in[3];
  const float* user_emb = (const float*)d_in[4];
  const float* W2  = (const float*)d_in[5];
  const float* b2  = (const float*)d_in[6];
  const float* W1  = (const float*)d_in[7];
  const float* b1  = (const float*)d_in[8];
  const float* Wf2 = (const float*)d_in[9];
  const float* bf2 = (const float*)d_in[10];
  cosrec_fused<<<BATCH, 256, 0, stream>>>(seq, usr, itm, item_emb, user_emb,
                                          W2, b2, W1, b1, Wf2, bf2,
                                          (float*)d_out);
}

// Round 2
// 154.243 us; speedup vs baseline: 1.0342x; 1.0186x over previous
//
#include <hip/hip_runtime.h>

typedef float f32x4 __attribute__((ext_vector_type(4)));
typedef short short8 __attribute__((ext_vector_type(8)));
typedef _Float16 half8 __attribute__((ext_vector_type(8)));

#define SEQ_LEN 32
#define EMBED_DIM 64
#define FC_DIM 100
#define BATCH 512
#define AS 136      // f16 row stride for A_s/B_s: 272B = odd*16B -> 2-way bank alias (free)
#define ES 72       // f16 row stride for emb_s: 144B -> 2-way bank alias (free)

// 16B MFMA operand fragment. f16 frag for mfma_f32_16x16x32_f16 is 8 halves (4 VGPRs).
union Frag {
  half8 h8;
  _Float16 h[8];
  short8 s;
  unsigned int u[4];
};

// All global tensors are fp32 (JAX defaults). Internal precision fp16, fp32 MFMA accum.
//
// One block per batch element. 256 threads = 4 waves, 2 blocks/CU (VGPR-bound).
// Structure (MFMA work is at its floor; this version attacks latency tails):
//  - ALL end-of-kernel global gathers (W2 rows, b2, user_emb, item_var, user_var)
//    hoisted to kernel entry: latency hides under phases A-D.
//  - Phase-B W1 fragments hoisted above the first barrier (pure loads).
//  - Phase E: quad-reduce via shfl_xor, 4 partial rows in LDS, one barrier,
//    Phase F sums the 4 rows directly (no x_s stage). 3 barriers total.
//  - Phase D: 2-deep B-row prefetch so ds_reads of ai+1 overlap MFMAs of ai.
__global__ __launch_bounds__(256, 2) void cosrec_fused(
    const int* __restrict__ seq_var, const int* __restrict__ user_var,
    const int* __restrict__ item_var, const float* __restrict__ item_emb,
    const float* __restrict__ user_emb, const float* __restrict__ W2,
    const float* __restrict__ b2, const float* __restrict__ W1,
    const float* __restrict__ b1, const float* __restrict__ Wf2,
    const float* __restrict__ bf2, float* __restrict__ out)
{
  __shared__ __align__(16) _Float16 A_s[SEQ_LEN * AS];
  __shared__ __align__(16) _Float16 B_s[SEQ_LEN * AS];
  __shared__ float red_s[4 * 112];
  __shared__ __align__(16) _Float16 emb_s[SEQ_LEN * ES];

  const int b = blockIdx.x;
  const int t = threadIdx.x;
  const int w = t >> 6;
  const int l = t & 63;
  const int l15 = l & 15;
  const int q = l >> 4;
  // fp16 1.0 in h-slot k=100 (ks=3, q=0, j=4 -> low half of dword u[2])
  const unsigned int biasbits = (q == 0) ? 0x00003C00u : 0u;

  // ---- Phase A: gather embedding rows (dependent chain: issue first) ----
  {
    const int r = t >> 3;                 // 0..31
    const int c0 = (t & 7) * 8;           // 8 cols per thread
    const int item = seq_var[b * SEQ_LEN + r];
    const float4 v0 = *(const float4*)(item_emb + item * EMBED_DIM + c0);
    const float4 v1 = *(const float4*)(item_emb + item * EMBED_DIM + c0 + 4);
    Frag e;
    e.h[0] = (_Float16)v0.x; e.h[1] = (_Float16)v0.y;
    e.h[2] = (_Float16)v0.z; e.h[3] = (_Float16)v0.w;
    e.h[4] = (_Float16)v1.x; e.h[5] = (_Float16)v1.y;
    e.h[6] = (_Float16)v1.z; e.h[7] = (_Float16)v1.w;
    *(short8*)(emb_s + r * ES + c0) = e.s;   // 16B-aligned
  }

  // ---- Hoisted Phase-F gathers (consumed at the very end; pure loads) ----
  float w2a = 0.f, w2b = 0.f, w2c = 0.f, uev = 0.f, b2v = 0.f;
  if (w < 3) {
    const int iv = item_var[b * 3 + w];
    const int uu = user_var[b];
    const float* w2p = W2 + iv * (FC_DIM + EMBED_DIM);
    w2a = w2p[l];
    w2b = w2p[64 + l];
    if (l < 36) w2c = w2p[128 + l];
    // lane needs uemb[l-36] when l>=36 (for tap 2) or uemb[l+28] when l<36 (tap 3)
    uev = user_emb[uu * EMBED_DIM + (l >= 36 ? l - 36 : l + 28)];
    b2v = b2[iv];
  }

  // ---- Wf2 -> register B-fragments (consumed in Phase D) ----
  // lane holds Wf2[g=nt*16+l15][k=ks*32+q*8+j]
  Frag wfrag[7][4];
  #pragma unroll
  for (int nt = 0; nt < 7; ++nt) {
    const int gg = nt * 16 + l15;
    const bool gok = (gg < FC_DIM);
    #pragma unroll
    for (int ks = 0; ks < 3; ++ks) {
      Frag f;
      if (gok) {                           // k = ks*32+q*8 .. +7 <= 95 < 100
        const float4 u0 = *(const float4*)(Wf2 + gg * FC_DIM + ks * 32 + q * 8);
        const float4 u1 = *(const float4*)(Wf2 + gg * FC_DIM + ks * 32 + q * 8 + 4);
        f.h[0] = (_Float16)u0.x; f.h[1] = (_Float16)u0.y;
        f.h[2] = (_Float16)u0.z; f.h[3] = (_Float16)u0.w;
        f.h[4] = (_Float16)u1.x; f.h[5] = (_Float16)u1.y;
        f.h[6] = (_Float16)u1.z; f.h[7] = (_Float16)u1.w;
      } else {
        f.u[0] = 0u; f.u[1] = 0u; f.u[2] = 0u; f.u[3] = 0u;
      }
      wfrag[nt][ks] = f;
    }
    // ks==3: k = 96 + q*8 + j. q==0 holds f=96..99 data, bf2 at k=100, rest 0.
    Frag f3;
    f3.u[0] = 0u; f3.u[1] = 0u; f3.u[2] = 0u; f3.u[3] = 0u;
    if (gok && q == 0) {
      const float4 u0 = *(const float4*)(Wf2 + gg * FC_DIM + 96);
      f3.h[0] = (_Float16)u0.x; f3.h[1] = (_Float16)u0.y;
      f3.h[2] = (_Float16)u0.z; f3.h[3] = (_Float16)u0.w;
      f3.h[4] = (_Float16)bf2[gg];         // bias folded into MFMA
    }
    wfrag[nt][3] = f3;
  }

  // ---- Hoisted Phase-B W1 fragments (above the barrier; dead after Phase B) ----
  Frag bfrh[4][2];
  float b1h[4];
  #pragma unroll
  for (int i = 0; i < 4; ++i) {
    const int nt = w + i * 4;
    b1h[i] = 0.f;
    bfrh[i][0].u[0] = 0u; bfrh[i][0].u[1] = 0u; bfrh[i][0].u[2] = 0u; bfrh[i][0].u[3] = 0u;
    bfrh[i][1].u[0] = 0u; bfrh[i][1].u[1] = 0u; bfrh[i][1].u[2] = 0u; bfrh[i][1].u[3] = 0u;
    if (nt < 13) {
      const int o = nt * 16 + l15;
      if (o < 2 * FC_DIM) {
        const int wr = (o < FC_DIM) ? o : o - FC_DIM;    // Wa = W1[:,:64], Wb = W1[:,64:]
        const int wc = (o < FC_DIM) ? 0 : 64;
        #pragma unroll
        for (int ks = 0; ks < 2; ++ks) {
          const float* p = W1 + wr * 128 + wc + ks * 32 + q * 8;  // 32B-aligned
          const float4 u0 = *(const float4*)p;
          const float4 u1 = *(const float4*)(p + 4);
          bfrh[i][ks].h[0] = (_Float16)u0.x; bfrh[i][ks].h[1] = (_Float16)u0.y;
          bfrh[i][ks].h[2] = (_Float16)u0.z; bfrh[i][ks].h[3] = (_Float16)u0.w;
          bfrh[i][ks].h[4] = (_Float16)u1.x; bfrh[i][ks].h[5] = (_Float16)u1.y;
          bfrh[i][ks].h[6] = (_Float16)u1.z; bfrh[i][ks].h[7] = (_Float16)u1.w;
        }
        if (o >= FC_DIM) b1h[i] = b1[o - FC_DIM];
      }
    }
  }

  // zero k-pad cols 100..127 of A_s/B_s (dword writes, 2 halves each)
  for (int i = t; i < SEQ_LEN * 14; i += 256) {
    const int r = i / 14, d = (i % 14) * 2;
    *(unsigned int*)(A_s + r * AS + FC_DIM + d) = 0u;
    *(unsigned int*)(B_s + r * AS + FC_DIM + d) = 0u;
  }
  __syncthreads();

  // ---- Phase B: first FC via MFMA (operands already in registers) ----
  #pragma unroll
  for (int i = 0; i < 4; ++i) {
    const int nt = w + i * 4;
    if (nt < 13) {
      const int o = nt * 16 + l15;
      #pragma unroll
      for (int mt = 0; mt < 2; ++mt) {
        Frag afr[2];
        #pragma unroll
        for (int ks = 0; ks < 2; ++ks)
          afr[ks].s = *(const short8*)(emb_s + (mt * 16 + l15) * ES + ks * 32 + q * 8);
        f32x4 acc = {0.f, 0.f, 0.f, 0.f};
        #pragma unroll
        for (int ks = 0; ks < 2; ++ks)
          acc = __builtin_amdgcn_mfma_f32_16x16x32_f16(afr[ks].h8, bfrh[i][ks].h8, acc, 0, 0, 0);
        const int row = mt * 16 + q * 4;   // D: col = lane&15, row = quad*4 + reg
        if (o < FC_DIM) {
          #pragma unroll
          for (int r = 0; r < 4; ++r)
            A_s[(row + r) * AS + o] = (_Float16)acc[r];
        } else if (o < 2 * FC_DIM) {
          #pragma unroll
          for (int r = 0; r < 4; ++r)
            B_s[(row + r) * AS + (o - FC_DIM)] = (_Float16)(acc[r] + b1h[i]);
        }
      }
    }
  }
  __syncthreads();

  // ---- Phase D: pair loop. Group = (c-half: 16 rows, 8 consecutive a's) ----
  float colsum[7];
  #pragma unroll
  for (int nt = 0; nt < 7; ++nt) colsum[nt] = 0.f;
  const half8 hzero = {};

  for (int g = w; g < 8; g += 4) {       // 2 groups per wave
    const int c = (g & 1) * 16 + l15;    // this lane's c-row (MFMA m-index)
    const int a0 = (g >> 1) * 8;
    Frag areg[4];                         // lane's A row in fragment order
    #pragma unroll
    for (int ks = 0; ks < 4; ++ks)
      areg[ks].s = *(const short8*)(A_s + c * AS + ks * 32 + q * 8);
    Frag brn[4];                          // prefetch B row for ai=0
    #pragma unroll
    for (int ks = 0; ks < 4; ++ks)
      brn[ks].s = *(const short8*)(B_s + a0 * AS + ks * 32 + q * 8);
    for (int ai = 0; ai < 8; ++ai) {
      Frag br[4];
      #pragma unroll
      for (int ks = 0; ks < 4; ++ks) br[ks] = brn[ks];
      if (ai < 7) {                       // prefetch next row under this ai's MFMAs
        const _Float16* bp = B_s + (a0 + ai + 1) * AS;
        #pragma unroll
        for (int ks = 0; ks < 4; ++ks)
          brn[ks].s = *(const short8*)(bp + ks * 32 + q * 8);
      }
      Frag hf[4];
      #pragma unroll
      for (int ks = 0; ks < 4; ++ks) {
        const half8 sum = areg[ks].h8 + br[ks].h8;          // v_pk_add_f16 x4
        hf[ks].h8 = __builtin_elementwise_max(sum, hzero);  // v_pk_max_f16 x4
      }
      hf[3].u[2] |= biasbits;                               // h=1.0 at k=100 (bias slot)
      #pragma unroll
      for (int nt = 0; nt < 7; ++nt) {
        f32x4 acc = {0.f, 0.f, 0.f, 0.f};
        #pragma unroll
        for (int ks = 0; ks < 4; ++ks)
          acc = __builtin_amdgcn_mfma_f32_16x16x32_f16(hf[ks].h8, wfrag[nt][ks].h8, acc, 0, 0, 0);
        #pragma unroll
        for (int r = 0; r < 4; ++r)
          colsum[nt] += fmaxf(acc[r], 0.f);   // second relu + M-reduce (bias in acc)
      }
    }
  }

  // ---- Phase E: quad-reduce in-wave, 4 partial rows to LDS, ONE barrier ----
  #pragma unroll
  for (int nt = 0; nt < 7; ++nt) {
    float v = colsum[nt];
    v += __shfl_xor(v, 16, 64);
    v += __shfl_xor(v, 32, 64);
    if (l < 16) red_s[w * 112 + nt * 16 + l] = v;
  }
  __syncthreads();

  // ---- Phase F: out[b,w] = b2[iv] + W2[iv,:].concat(x, uemb) (loads hoisted) ----
  if (w < 3) {
    float xa = red_s[l] + red_s[112 + l] + red_s[224 + l] + red_s[336 + l];
    float xb, xc;
    if (l < 36) {
      const int i2 = 64 + l;
      xb = red_s[i2] + red_s[112 + i2] + red_s[224 + i2] + red_s[336 + i2];
      xc = uev;                    // concat idx l+128 -> uemb[l+28]
    } else {
      xb = uev;                    // concat idx l+64 -> uemb[l-36]
      xc = 0.f;
    }
    float partial = w2a * xa + w2b * xb + w2c * xc;
    #pragma unroll
    for (int off = 32; off > 0; off >>= 1)
      partial += __shfl_down(partial, off, 64);
    if (l == 0) out[b * 3 + w] = partial + b2v;
  }
}

extern "C" void kernel_launch(void* const* d_in, const int* in_sizes, int n_in,
                              void* d_out, int out_size, void* d_ws, size_t ws_size,
                              hipStream_t stream) {
  const int* seq = (const int*)d_in[0];
  const int* usr = (const int*)d_in[1];
  const int* itm = (const int*)d_in[2];
  const float* item_emb = (const float*)d_in[3];
  const float* user_emb = (const float*)d_in[4];
  const float* W2  = (const float*)d_in[5];
  const float* b2  = (const float*)d_in[6];
  const float* W1  = (const float*)d_in[7];
  const float* b1  = (const float*)d_in[8];
  const float* Wf2 = (const float*)d_in[9];
  const float* bf2 = (const float*)d_in[10];
  cosrec_fused<<<BATCH, 256, 0, stream>>>(seq, usr, itm, item_emb, user_emb,
                                          W2, b2, W1, b1, Wf2, bf2,
                                          (float*)d_out);
}

// Round 5
// 153.275 us; speedup vs baseline: 1.0408x; 1.0063x over previous
//
#include <hip/hip_runtime.h>

typedef float f32x4 __attribute__((ext_vector_type(4)));
typedef short short8 __attribute__((ext_vector_type(8)));
typedef _Float16 half8 __attribute__((ext_vector_type(8)));
typedef _Float16 half4v __attribute__((ext_vector_type(4)));

#define SEQ_LEN 32
#define EMBED_DIM 64
#define FC_DIM 100
#define BATCH 512
#define AS 136      // f16 row stride for A_s/B_s: 272B = odd*16B -> 2-way bank alias (free)
#define ES 72       // f16 row stride for emb_s: 144B -> 2-way bank alias (free)

// 16B MFMA operand fragment (mfma_f32_16x16x32_f16: 8 halves / 4 VGPRs).
union Frag {
  half8 h8;
  _Float16 h[8];
  short8 s;
  unsigned int u[4];
};
// 8B scratch for the f=96..99 tail data (2 dwords).
union Frag4 {
  half4v h4;
  _Float16 h[4];
  unsigned int u[2];
};

// All global tensors are fp32 (JAX defaults). Internal precision fp16, fp32 MFMA accum.
//
// One block per batch element. 256 threads = 4 waves, 2 blocks/CU (VGPR-bound).
// Phase D second FC: K = 4x32 = 128 via mfma_f32_16x16x32_f16 (verified layout:
// A lane holds m=l&15, k=ks*32+q*8+j). The 4th K-fragment is built IN-REGISTER:
// q==0 lanes carry relu data f=96..99 (k=96..99) + 1.0 at k=100 (bias slot,
// pairs with bf2[g] on the B side); q>=1 lanes are zero. So no pad columns of
// A_s/B_s are ever written or read (pad-fill loop deleted; tail reads are two
// broadcast dwords instead of a b128).
//  - All end-of-kernel gathers (W2 rows, b2, user_emb, item_var, user_var)
//    hoisted to kernel entry.
//  - Phase-B W1 fragments hoisted above the first barrier.
//  - Phase E: quad-reduce via shfl_xor, 4 partial rows in LDS, one barrier.
//  - Phase D: 2-deep B-row prefetch.
__global__ __launch_bounds__(256, 2) void cosrec_fused(
    const int* __restrict__ seq_var, const int* __restrict__ user_var,
    const int* __restrict__ item_var, const float* __restrict__ item_emb,
    const float* __restrict__ user_emb, const float* __restrict__ W2,
    const float* __restrict__ b2, const float* __restrict__ W1,
    const float* __restrict__ b1, const float* __restrict__ Wf2,
    const float* __restrict__ bf2, float* __restrict__ out)
{
  __shared__ __align__(16) _Float16 A_s[SEQ_LEN * AS];
  __shared__ __align__(16) _Float16 B_s[SEQ_LEN * AS];
  __shared__ float red_s[4 * 112];
  __shared__ __align__(16) _Float16 emb_s[SEQ_LEN * ES];

  const int b = blockIdx.x;
  const int t = threadIdx.x;
  const int w = t >> 6;
  const int l = t & 63;
  const int l15 = l & 15;
  const int q = l >> 4;
  const bool qz = (q == 0);

  // ---- Phase A: gather embedding rows (dependent chain: issue first) ----
  {
    const int r = t >> 3;                 // 0..31
    const int c0 = (t & 7) * 8;           // 8 cols per thread
    const int item = seq_var[b * SEQ_LEN + r];
    const float4 v0 = *(const float4*)(item_emb + item * EMBED_DIM + c0);
    const float4 v1 = *(const float4*)(item_emb + item * EMBED_DIM + c0 + 4);
    Frag e;
    e.h[0] = (_Float16)v0.x; e.h[1] = (_Float16)v0.y;
    e.h[2] = (_Float16)v0.z; e.h[3] = (_Float16)v0.w;
    e.h[4] = (_Float16)v1.x; e.h[5] = (_Float16)v1.y;
    e.h[6] = (_Float16)v1.z; e.h[7] = (_Float16)v1.w;
    *(short8*)(emb_s + r * ES + c0) = e.s;   // 16B-aligned
  }

  // ---- Hoisted Phase-F gathers (consumed at the very end; pure loads) ----
  float w2a = 0.f, w2b = 0.f, w2c = 0.f, uev = 0.f, b2v = 0.f;
  if (w < 3) {
    const int iv = item_var[b * 3 + w];
    const int uu = user_var[b];
    const float* w2p = W2 + iv * (FC_DIM + EMBED_DIM);
    w2a = w2p[l];
    w2b = w2p[64 + l];
    if (l < 36) w2c = w2p[128 + l];
    // lane needs uemb[l-36] when l>=36 (tap 2) or uemb[l+28] when l<36 (tap 3)
    uev = user_emb[uu * EMBED_DIM + (l >= 36 ? l - 36 : l + 28)];
    b2v = b2[iv];
  }

  // ---- Wf2 -> register B-fragments (consumed in Phase D) ----
  // lane holds Wf2[g=nt*16+l15][k=ks*32+q*8+j]. ks==3: only q==0 is nonzero
  // (h[0..3] = Wf2[gg][96..99], h[4] = bf2[gg] at k=100).
  Frag wfrag[7][4];
  #pragma unroll
  for (int nt = 0; nt < 7; ++nt) {
    const int gg = nt * 16 + l15;
    const bool gok = (gg < FC_DIM);
    #pragma unroll
    for (int ks = 0; ks < 3; ++ks) {
      Frag f;
      if (gok) {
        const float4 u0 = *(const float4*)(Wf2 + gg * FC_DIM + ks * 32 + q * 8);
        const float4 u1 = *(const float4*)(Wf2 + gg * FC_DIM + ks * 32 + q * 8 + 4);
        f.h[0] = (_Float16)u0.x; f.h[1] = (_Float16)u0.y;
        f.h[2] = (_Float16)u0.z; f.h[3] = (_Float16)u0.w;
        f.h[4] = (_Float16)u1.x; f.h[5] = (_Float16)u1.y;
        f.h[6] = (_Float16)u1.z; f.h[7] = (_Float16)u1.w;
      } else {
        f.u[0] = 0u; f.u[1] = 0u; f.u[2] = 0u; f.u[3] = 0u;
      }
      wfrag[nt][ks] = f;
    }
    Frag f3;
    f3.u[0] = 0u; f3.u[1] = 0u; f3.u[2] = 0u; f3.u[3] = 0u;
    if (gok && q == 0) {
      const float4 u0 = *(const float4*)(Wf2 + gg * FC_DIM + 96);
      f3.h[0] = (_Float16)u0.x; f3.h[1] = (_Float16)u0.y;
      f3.h[2] = (_Float16)u0.z; f3.h[3] = (_Float16)u0.w;
      f3.h[4] = (_Float16)bf2[gg];         // bias folded into MFMA at k=100
    }
    wfrag[nt][3] = f3;
  }

  // ---- Hoisted Phase-B W1 fragments (above the barrier; dead after Phase B) ----
  Frag bfrh[4][2];
  float b1h[4];
  #pragma unroll
  for (int i = 0; i < 4; ++i) {
    const int nt = w + i * 4;
    b1h[i] = 0.f;
    bfrh[i][0].u[0] = 0u; bfrh[i][0].u[1] = 0u; bfrh[i][0].u[2] = 0u; bfrh[i][0].u[3] = 0u;
    bfrh[i][1].u[0] = 0u; bfrh[i][1].u[1] = 0u; bfrh[i][1].u[2] = 0u; bfrh[i][1].u[3] = 0u;
    if (nt < 13) {
      const int o = nt * 16 + l15;
      if (o < 2 * FC_DIM) {
        const int wr = (o < FC_DIM) ? o : o - FC_DIM;    // Wa = W1[:,:64], Wb = W1[:,64:]
        const int wc = (o < FC_DIM) ? 0 : 64;
        #pragma unroll
        for (int ks = 0; ks < 2; ++ks) {
          const float* p = W1 + wr * 128 + wc + ks * 32 + q * 8;  // 32B-aligned
          const float4 u0 = *(const float4*)p;
          const float4 u1 = *(const float4*)(p + 4);
          bfrh[i][ks].h[0] = (_Float16)u0.x; bfrh[i][ks].h[1] = (_Float16)u0.y;
          bfrh[i][ks].h[2] = (_Float16)u0.z; bfrh[i][ks].h[3] = (_Float16)u0.w;
          bfrh[i][ks].h[4] = (_Float16)u1.x; bfrh[i][ks].h[5] = (_Float16)u1.y;
          bfrh[i][ks].h[6] = (_Float16)u1.z; bfrh[i][ks].h[7] = (_Float16)u1.w;
        }
        if (o >= FC_DIM) b1h[i] = b1[o - FC_DIM];
      }
    }
  }
  __syncthreads();

  // ---- Phase B: first FC via MFMA (operands already in registers) ----
  #pragma unroll
  for (int i = 0; i < 4; ++i) {
    const int nt = w + i * 4;
    if (nt < 13) {
      const int o = nt * 16 + l15;
      #pragma unroll
      for (int mt = 0; mt < 2; ++mt) {
        Frag afr[2];
        #pragma unroll
        for (int ks = 0; ks < 2; ++ks)
          afr[ks].s = *(const short8*)(emb_s + (mt * 16 + l15) * ES + ks * 32 + q * 8);
        f32x4 acc = {0.f, 0.f, 0.f, 0.f};
        #pragma unroll
        for (int ks = 0; ks < 2; ++ks)
          acc = __builtin_amdgcn_mfma_f32_16x16x32_f16(afr[ks].h8, bfrh[i][ks].h8, acc, 0, 0, 0);
        const int row = mt * 16 + q * 4;   // D: col = lane&15, row = quad*4 + reg
        if (o < FC_DIM) {
          #pragma unroll
          for (int r = 0; r < 4; ++r)
            A_s[(row + r) * AS + o] = (_Float16)acc[r];
        } else if (o < 2 * FC_DIM) {
          #pragma unroll
          for (int r = 0; r < 4; ++r)
            B_s[(row + r) * AS + (o - FC_DIM)] = (_Float16)(acc[r] + b1h[i]);
        }
      }
    }
  }
  __syncthreads();

  // ---- Phase D: pair loop. Group = (c-half: 16 rows, 8 consecutive a's) ----
  float colsum[7];
  #pragma unroll
  for (int nt = 0; nt < 7; ++nt) colsum[nt] = 0.f;
  const half8 hzero = {};
  const half4v h4zero = {};

  for (int g = w; g < 8; g += 4) {       // 2 groups per wave
    const int c = (g & 1) * 16 + l15;    // this lane's c-row (MFMA m-index)
    const int a0 = (g >> 1) * 8;
    Frag areg[3];                         // lane's A row, f=0..95 in fragment order
    #pragma unroll
    for (int ks = 0; ks < 3; ++ks)
      areg[ks].s = *(const short8*)(A_s + c * AS + ks * 32 + q * 8);
    Frag4 atail;                          // f=96..99 (same addr across quads)
    atail.u[0] = *(const unsigned int*)(A_s + c * AS + 96);
    atail.u[1] = *(const unsigned int*)(A_s + c * AS + 98);
    Frag brn[3];                          // prefetch B row for ai=0
    Frag4 btn;
    #pragma unroll
    for (int ks = 0; ks < 3; ++ks)
      brn[ks].s = *(const short8*)(B_s + a0 * AS + ks * 32 + q * 8);
    btn.u[0] = *(const unsigned int*)(B_s + a0 * AS + 96);
    btn.u[1] = *(const unsigned int*)(B_s + a0 * AS + 98);
    for (int ai = 0; ai < 8; ++ai) {
      Frag br[3];
      Frag4 bt;
      #pragma unroll
      for (int ks = 0; ks < 3; ++ks) br[ks] = brn[ks];
      bt = btn;
      if (ai < 7) {                       // prefetch next row under this ai's MFMAs
        const _Float16* bp = B_s + (a0 + ai + 1) * AS;
        #pragma unroll
        for (int ks = 0; ks < 3; ++ks)
          brn[ks].s = *(const short8*)(bp + ks * 32 + q * 8);
        btn.u[0] = *(const unsigned int*)(bp + 96);
        btn.u[1] = *(const unsigned int*)(bp + 98);
      }
      Frag hf[3];
      #pragma unroll
      for (int ks = 0; ks < 3; ++ks) {
        const half8 sum = areg[ks].h8 + br[ks].h8;          // v_pk_add_f16 x4
        hf[ks].h8 = __builtin_elementwise_max(sum, hzero);  // v_pk_max_f16 x4
      }
      // 4th K-fragment in-register: q==0 -> {relu f=96..99, 1.0 at k=100, 0};
      // q>=1 -> all zero (k=104..127 unused).
      Frag4 t4;
      t4.h4 = __builtin_elementwise_max(atail.h4 + bt.h4, h4zero);
      Frag hf3;
      hf3.u[0] = qz ? t4.u[0] : 0u;
      hf3.u[1] = qz ? t4.u[1] : 0u;
      hf3.u[2] = qz ? 0x00003C00u : 0u;   // fp16 1.0 at h[4] (k=100)
      hf3.u[3] = 0u;
      #pragma unroll
      for (int nt = 0; nt < 7; ++nt) {
        f32x4 acc = {0.f, 0.f, 0.f, 0.f};
        #pragma unroll
        for (int ks = 0; ks < 3; ++ks)
          acc = __builtin_amdgcn_mfma_f32_16x16x32_f16(hf[ks].h8, wfrag[nt][ks].h8, acc, 0, 0, 0);
        acc = __builtin_amdgcn_mfma_f32_16x16x32_f16(hf3.h8, wfrag[nt][3].h8, acc, 0, 0, 0);
        #pragma unroll
        for (int r = 0; r < 4; ++r)
          colsum[nt] += fmaxf(acc[r], 0.f);   // second relu + M-reduce (bias in acc)
      }
    }
  }

  // ---- Phase E: quad-reduce in-wave, 4 partial rows to LDS, ONE barrier ----
  #pragma unroll
  for (int nt = 0; nt < 7; ++nt) {
    float v = colsum[nt];
    v += __shfl_xor(v, 16, 64);
    v += __shfl_xor(v, 32, 64);
    if (l < 16) red_s[w * 112 + nt * 16 + l] = v;
  }
  __syncthreads();

  // ---- Phase F: out[b,w] = b2[iv] + W2[iv,:].concat(x, uemb) (loads hoisted) ----
  if (w < 3) {
    float xa = red_s[l] + red_s[112 + l] + red_s[224 + l] + red_s[336 + l];
    float xb, xc;
    if (l < 36) {
      const int i2 = 64 + l;
      xb = red_s[i2] + red_s[112 + i2] + red_s[224 + i2] + red_s[336 + i2];
      xc = uev;                    // concat idx l+128 -> uemb[l+28]
    } else {
      xb = uev;                    // concat idx l+64 -> uemb[l-36]
      xc = 0.f;
    }
    float partial = w2a * xa + w2b * xb + w2c * xc;
    #pragma unroll
    for (int off = 32; off > 0; off >>= 1)
      partial += __shfl_down(partial, off, 64);
    if (l == 0) out[b * 3 + w] = partial + b2v;
  }
}

extern "C" void kernel_launch(void* const* d_in, const int* in_sizes, int n_in,
                              void* d_out, int out_size, void* d_ws, size_t ws_size,
                              hipStream_t stream) {
  const int* seq = (const int*)d_in[0];
  const int* usr = (const int*)d_in[1];
  const int* itm = (const int*)d_in[2];
  const float* item_emb = (const float*)d_in[3];
  const float* user_emb = (const float*)d_in[4];
  const float* W2  = (const float*)d_in[5];
  const float* b2  = (const float*)d_in[6];
  const float* W1  = (const float*)d_in[7];
  const float* b1  = (const float*)d_in[8];
  const float* Wf2 = (const float*)d_in[9];
  const float* bf2 = (const float*)d_in[10];
  cosrec_fused<<<BATCH, 256, 0, stream>>>(seq, usr, itm, item_emb, user_emb,
                                          W2, b2, W1, b1, Wf2, bf2,
                                          (float*)d_out);
}